// Round 17
// baseline (287.458 us; speedup 1.0000x reference)
//
#include <hip/hip_runtime.h>
#include <math.h>

#define BB 4
#define LL 1024
#define RR 4
#define DD 1024
#define EPSV 1e-6f

typedef short s16x8 __attribute__((ext_vector_type(8)));
typedef float f32x4 __attribute__((ext_vector_type(4)));
typedef unsigned short u16;

__device__ inline unsigned short f2bf(float x) {
  unsigned u = __builtin_bit_cast(unsigned, x);
  unsigned r = (u + 0x7fffu + ((u >> 16) & 1u)) >> 16;
  return (unsigned short)r;
}
__device__ inline float bf2f(u16 x) {
  return __builtin_bit_cast(float, (unsigned)x << 16);
}
__device__ inline float fast_tanh(float x) {
  float e = __expf(2.f * x);
  return 1.f - 2.f / (e + 1.f);
}

__device__ inline float wred_xor(float v) {
#pragma unroll
  for (int off = 1; off < 64; off <<= 1) v += __shfl_xor(v, off);
  return v;
}

__device__ inline void gload_lds16(const u16* g, u16* l) {
  __builtin_amdgcn_global_load_lds(
      (const __attribute__((address_space(1))) unsigned int*)g,
      (__attribute__((address_space(3))) unsigned int*)l, 16, 0, 0);
}

// ---------------- width (hyper-connection), wave-per-row, interleaved cvt ----------------
// Reduction-batched: all 28 wred_xor chains (4 ss + 24 dots) issue together.
template<int NP, bool CVT>
__global__ __launch_bounds__(256) void width_kernel(
    const float* __restrict__ Hin,
    const u16* __restrict__ mixrest_in,
    const float* __restrict__ beta_in,
    const u16* __restrict__ pp,
    const float* __restrict__ hc_norm_w,
    const float* __restrict__ alpha_fn,
    const float* __restrict__ beta_fn,
    const float* __restrict__ a_scale,
    const float* __restrict__ b_scale,
    const float* __restrict__ s_alpha,
    const float* __restrict__ s_beta,
    const float* __restrict__ post_norm_w,
    u16* __restrict__ mixrest_out,
    float* __restrict__ beta_out,
    u16* __restrict__ x_out,
    const float* __restrict__ cvt_s0, const float* __restrict__ cvt_s1,
    const float* __restrict__ cvt_s2, const float* __restrict__ cvt_s3,
    u16* __restrict__ cvt_d0, u16* __restrict__ cvt_d1,
    u16* __restrict__ cvt_d2, u16* __restrict__ cvt_d3)
{
  if (CVT && (blockIdx.x & 1)) {
    const int n0 = 786432, n1 = 262144, n2 = 1048576, n3 = 1048576;
    const int total = n0 + n1 + n2 + n3;
    for (int i = (blockIdx.x >> 1) * 256 + threadIdx.x; i < total; i += 1024 * 256) {
      const float4* src; ushort4* dst; int j;
      if (i < n0)                { src = (const float4*)cvt_s0; dst = (ushort4*)cvt_d0; j = i; }
      else if (i < n0 + n1)      { src = (const float4*)cvt_s1; dst = (ushort4*)cvt_d1; j = i - n0; }
      else if (i < n0 + n1 + n2) { src = (const float4*)cvt_s2; dst = (ushort4*)cvt_d2; j = i - n0 - n1; }
      else                       { src = (const float4*)cvt_s3; dst = (ushort4*)cvt_d3; j = i - n0 - n1 - n2; }
      float4 v = src[j];
      ushort4 o;
      o.x = f2bf(v.x); o.y = f2bf(v.y); o.z = f2bf(v.z); o.w = f2bf(v.w);
      dst[j] = o;
    }
    return;
  }
  const int blw = CVT ? (blockIdx.x >> 1) : blockIdx.x;

  const size_t MN = (size_t)4096 * 1024;
  const int l = threadIdx.x & 63, w = threadIdx.x >> 6;
  const int bl = blw * 4 + w;
  const int d0 = l << 2;

  float4 h[4][4];
  if (NP > 0) {
    float be[4];
#pragma unroll
    for (int n = 0; n < 4; ++n) be[n] = beta_in[bl * 4 + n];
#pragma unroll
    for (int i = 0; i < 4; ++i) {
      const int d = i * 256 + d0;
      float4 s; s.x = 0.f; s.y = 0.f; s.z = 0.f; s.w = 0.f;
#pragma unroll
      for (int p = 0; p < (NP > 0 ? NP : 1); ++p) {
        ushort4 v = *(const ushort4*)&pp[p * MN + (size_t)bl * 1024 + d];
        s.x += bf2f(v.x); s.y += bf2f(v.y); s.z += bf2f(v.z); s.w += bf2f(v.w);
      }
#pragma unroll
      for (int n = 0; n < 4; ++n) {
        ushort4 mr = *(const ushort4*)&mixrest_in[(size_t)bl * 4096 + n * 1024 + d];
        h[n][i].x = be[n] * s.x + bf2f(mr.x);
        h[n][i].y = be[n] * s.y + bf2f(mr.y);
        h[n][i].z = be[n] * s.z + bf2f(mr.z);
        h[n][i].w = be[n] * s.w + bf2f(mr.w);
      }
    }
  } else {
#pragma unroll
    for (int i = 0; i < 4; ++i) {
      const int d = i * 256 + d0;
#pragma unroll
      for (int n = 0; n < 4; ++n)
        h[n][i] = *(const float4*)&Hin[(size_t)bl * 4096 + n * 1024 + d];
    }
  }

  // local sum-of-squares accumulation (no reduction yet)
  float ssl[4];
#pragma unroll
  for (int n = 0; n < 4; ++n) {
    float a = 0.f;
#pragma unroll
    for (int i = 0; i < 4; ++i)
      a += h[n][i].x * h[n][i].x + h[n][i].y * h[n][i].y +
           h[n][i].z * h[n][i].z + h[n][i].w * h[n][i].w;
    ssl[n] = a;
  }

  // dot accumulation (independent of inv — factored out)
  float dots[4][6];
#pragma unroll
  for (int n = 0; n < 4; ++n)
#pragma unroll
    for (int k = 0; k < 6; ++k) dots[n][k] = 0.f;
#pragma unroll
  for (int i = 0; i < 4; ++i) {
    const int d = i * 256 + d0;
    float4 nw = *(const float4*)&hc_norm_w[d];
    float4 bfv4 = *(const float4*)&beta_fn[d];
    float4 A0 = *(const float4*)&alpha_fn[d * 5];
    float4 A1 = *(const float4*)&alpha_fn[d * 5 + 4];
    float4 A2 = *(const float4*)&alpha_fn[d * 5 + 8];
    float4 A3 = *(const float4*)&alpha_fn[d * 5 + 12];
    float4 A4 = *(const float4*)&alpha_fn[d * 5 + 16];
    const float af[4][5] = {
        {A0.x, A0.y, A0.z, A0.w, A1.x},
        {A1.y, A1.z, A1.w, A2.x, A2.y},
        {A2.z, A2.w, A3.x, A3.y, A3.z},
        {A3.w, A4.x, A4.y, A4.z, A4.w}};
    const float nwv[4] = {nw.x, nw.y, nw.z, nw.w};
    const float bfl[4] = {bfv4.x, bfv4.y, bfv4.z, bfv4.w};
#pragma unroll
    for (int j = 0; j < 4; ++j) {
      const float wj = nwv[j];
#pragma unroll
      for (int n = 0; n < 4; ++n) {
        const float hw = (j == 0 ? h[n][i].x : j == 1 ? h[n][i].y : j == 2 ? h[n][i].z : h[n][i].w) * wj;
        dots[n][0] += hw * af[j][0];
        dots[n][1] += hw * af[j][1];
        dots[n][2] += hw * af[j][2];
        dots[n][3] += hw * af[j][3];
        dots[n][4] += hw * af[j][4];
        dots[n][5] += hw * bfl[j];
      }
    }
  }

  // BATCHED reductions: 4 ss + 24 dots issue together (28 independent chains)
  float ssr[4], dr[4][6];
#pragma unroll
  for (int n = 0; n < 4; ++n) ssr[n] = wred_xor(ssl[n]);
#pragma unroll
  for (int n = 0; n < 4; ++n)
#pragma unroll
    for (int k = 0; k < 6; ++k) dr[n][k] = wred_xor(dots[n][k]);

  const float as = a_scale[0], bs = b_scale[0];
  float alpha[4][5], betav[4];
#pragma unroll
  for (int n = 0; n < 4; ++n) {
    const float invn = 1.f / (sqrtf(ssr[n] * (1.f / 1024.f)) + EPSV);
#pragma unroll
    for (int k = 0; k < 5; ++k)
      alpha[n][k] = fast_tanh(dr[n][k] * invn) * as + s_alpha[n * 5 + k];
    betav[n] = fast_tanh(dr[n][5] * invn) * bs + s_beta[n];
  }
  if (l == 0) {
#pragma unroll
    for (int n = 0; n < 4; ++n) beta_out[bl * 4 + n] = betav[n];
  }

  float4 mix0[4];
#pragma unroll
  for (int i = 0; i < 4; ++i) {
    const int d = i * 256 + d0;
#pragma unroll
    for (int k = 0; k < 5; ++k) {
      const float c0 = alpha[0][k], c1 = alpha[1][k], c2 = alpha[2][k], c3 = alpha[3][k];
      float4 mv;
      mv.x = c0 * h[0][i].x + c1 * h[1][i].x + c2 * h[2][i].x + c3 * h[3][i].x;
      mv.y = c0 * h[0][i].y + c1 * h[1][i].y + c2 * h[2][i].y + c3 * h[3][i].y;
      mv.z = c0 * h[0][i].z + c1 * h[1][i].z + c2 * h[2][i].z + c3 * h[3][i].z;
      mv.w = c0 * h[0][i].w + c1 * h[1][i].w + c2 * h[2][i].w + c3 * h[3][i].w;
      if (k == 0) {
        mix0[i] = mv;
      } else {
        ushort4 ov;
        ov.x = f2bf(mv.x); ov.y = f2bf(mv.y); ov.z = f2bf(mv.z); ov.w = f2bf(mv.w);
        *(ushort4*)&mixrest_out[(size_t)bl * 4096 + (size_t)(k - 1) * 1024 + d] = ov;
      }
    }
  }

  float a0s = 0.f;
#pragma unroll
  for (int i = 0; i < 4; ++i)
    a0s += mix0[i].x * mix0[i].x + mix0[i].y * mix0[i].y +
           mix0[i].z * mix0[i].z + mix0[i].w * mix0[i].w;
  a0s = wred_xor(a0s);
  const float iv0 = 1.f / (sqrtf(a0s * (1.f / 1024.f)) + EPSV);
#pragma unroll
  for (int i = 0; i < 4; ++i) {
    const int d = i * 256 + d0;
    float4 pw = *(const float4*)&post_norm_w[d];
    ushort4 ov;
    ov.x = f2bf(pw.x * mix0[i].x * iv0);
    ov.y = f2bf(pw.y * mix0[i].y * iv0);
    ov.z = f2bf(pw.z * mix0[i].z * iv0);
    ov.w = f2bf(pw.w * mix0[i].w * iv0);
    *(ushort4*)&x_out[(size_t)bl * 1024 + d] = ov;
  }
}

// ---------------- bf16 GEMM 128x128 (R7 proven) — all four GEMMs ----------------
template<int EPI, int SPLIT>
__global__ __launch_bounds__(256, 4) void gemm_bt_kernel(
    const u16* __restrict__ A, const u16* __restrict__ W,
    u16* __restrict__ Cb, u16* __restrict__ Vt,
    int M, int N, int K)
{
  __shared__ __align__(16) u16 LDSb[2][2][128 * 32];
  const int tn = N >> 7, tm = M >> 7;
  int bid = blockIdx.x;
  const int nwg = gridDim.x;
  if ((nwg & 7) == 0) bid = (bid & 7) * (nwg >> 3) + (bid >> 3);
  const int ts = tm * tn;
  const int sK = bid / ts;
  const int tb = bid - sK * ts;
  const int bm = tb / tn, bn = tb % tn;
  const int Kc = K / SPLIT;
  const int kbeg = sK * Kc;

  const int t = threadIdx.x, l = t & 63, w = t >> 6;
  const int wr = w >> 1, wc = w & 1;
  const int m0 = bm << 7, n0 = bn << 7;
  const int ssc = (((l & 3) ^ ((l >> 3) & 3)) << 3);
  const int srA = m0 + (w << 5) + (l >> 2);
  const int srB = n0 + (w << 5) + (l >> 2);
  const int ldso = (w << 10);
  const int fr = l & 15, g4 = l >> 4;
  const int fc8 = ((g4 ^ ((l >> 1) & 3)) << 3);

  f32x4 acc[4][4];
#pragma unroll
  for (int i = 0; i < 4; ++i)
#pragma unroll
    for (int j = 0; j < 4; ++j)
#pragma unroll
      for (int e = 0; e < 4; ++e) acc[i][j][e] = 0.f;

  const u16* pa0 = A + (size_t)srA * K + kbeg + ssc;
  const u16* pa1 = A + (size_t)(srA + 16) * K + kbeg + ssc;
  const u16* pb0 = W + (size_t)srB * K + kbeg + ssc;
  const u16* pb1 = W + (size_t)(srB + 16) * K + kbeg + ssc;

#define STAGE(buf, koff)                                   \
  do {                                                     \
    gload_lds16(pa0 + (koff), &LDSb[buf][0][ldso]);        \
    gload_lds16(pa1 + (koff), &LDSb[buf][0][ldso + 512]);  \
    gload_lds16(pb0 + (koff), &LDSb[buf][1][ldso]);        \
    gload_lds16(pb1 + (koff), &LDSb[buf][1][ldso + 512]);  \
  } while (0)

  const int nt = Kc >> 5;
  STAGE(0, 0);
  int cur = 0;
  for (int kt = 0; kt < nt; ++kt) {
    if (kt + 1 < nt) {
      STAGE(cur ^ 1, (kt + 1) << 5);
      asm volatile("s_waitcnt vmcnt(4)" ::: "memory");
    } else {
      asm volatile("s_waitcnt vmcnt(0)" ::: "memory");
    }
    __builtin_amdgcn_s_barrier();
    __builtin_amdgcn_sched_barrier(0);
    s16x8 af[4], bfr[4];
#pragma unroll
    for (int m = 0; m < 4; ++m)
      af[m] = *(const s16x8*)(&LDSb[cur][0][(wr * 64 + m * 16 + fr) * 32 + fc8]);
#pragma unroll
    for (int n = 0; n < 4; ++n)
      bfr[n] = *(const s16x8*)(&LDSb[cur][1][(wc * 64 + n * 16 + fr) * 32 + fc8]);
#pragma unroll
    for (int m = 0; m < 4; ++m)
#pragma unroll
      for (int n = 0; n < 4; ++n)
        acc[m][n] = __builtin_amdgcn_mfma_f32_16x16x32_bf16(af[m], bfr[n], acc[m][n], 0, 0, 0);
    asm volatile("s_waitcnt lgkmcnt(0)" ::: "memory");
    __builtin_amdgcn_sched_barrier(0);
    __builtin_amdgcn_s_barrier();
    cur ^= 1;
  }
#undef STAGE

  if (EPI == 2 && n0 >= 2048) {
    const int rbv = m0 + wr * 64 + (g4 << 2);
    const int cbv = n0 + wc * 64 + fr;
#pragma unroll
    for (int m = 0; m < 4; ++m)
#pragma unroll
      for (int n = 0; n < 4; ++n) {
        int cc = cbv + n * 16 - 2048;
        int hh = cc >> 6, dd = cc & 63;
        int r0 = rbv + m * 16;
        ushort4 ov;
        ov.x = f2bf(acc[m][n][0]); ov.y = f2bf(acc[m][n][1]);
        ov.z = f2bf(acc[m][n][2]); ov.w = f2bf(acc[m][n][3]);
        *(ushort4*)&Vt[((size_t)((r0 >> 10) * 16 + hh) * 64 + dd) * 1024 + (r0 & 1023)] = ov;
      }
    return;
  }

  float* scr = (float*)LDSb;
  const int strideN = (EPI == 2) ? 2048 : N;
  u16* Cout = (SPLIT > 1) ? (Cb + (size_t)sK * M * N) : Cb;
#pragma unroll
  for (int r = 0; r < 2; ++r) {
    __syncthreads();
    if (wr == r) {
#pragma unroll
      for (int m = 0; m < 4; ++m)
#pragma unroll
        for (int n = 0; n < 4; ++n)
#pragma unroll
          for (int j = 0; j < 4; ++j) {
            int lr = m * 16 + (g4 << 2) + j;
            int col = wc * 64 + n * 16 + fr;
            scr[lr * 128 + (col ^ ((((lr >> 2) & 7)) << 3))] = acc[m][n][j];
          }
    }
    __syncthreads();
#pragma unroll
    for (int it = 0; it < 4; ++it) {
      int lr = it * 16 + (t >> 4);
      int key8 = ((lr >> 2) & 7) << 3;
      int lc = (t & 15) << 3;
      int cb0 = (lc ^ key8);
      f32x4 v0 = *(const f32x4*)&scr[lr * 128 + cb0];
      f32x4 v1 = *(const f32x4*)&scr[lr * 128 + cb0 + 4];
      float vv[8] = {v0[0], v0[1], v0[2], v0[3], v1[0], v1[1], v1[2], v1[3]};
      s16x8 ov;
#pragma unroll
      for (int c = 0; c < 8; ++c) {
        float v = vv[c];
        if (EPI == 1) v = 0.5f * v * (1.f + erff(v * 0.70710678118f));
        ov[c] = (short)f2bf(v);
      }
      size_t gr = (size_t)(m0 + r * 64 + lr);
      *(s16x8*)&Cout[gr * strideN + n0 + lc] = ov;
    }
  }
}

// ---------------- MFMA flash attention, causal (R9 proven) ----------------
__global__ __launch_bounds__(256) void attn_mfma_kernel(
    const u16* __restrict__ qk, const u16* __restrict__ Vt, u16* __restrict__ out)
{
  const int id = blockIdx.x;
  const int hb = id & 63, qt0 = id >> 6;
  const int b = hb >> 4, h = hb & 15;
  const int qt = (h & 1) ? (15 - qt0) : qt0;
  const int t = threadIdx.x, l = t & 63, w = t >> 6;
  const int q0 = qt << 6;
  __shared__ __align__(16) u16 Ks[2][64 * 64];
  __shared__ __align__(16) u16 Vs[2][64 * 64];
  __shared__ __align__(16) u16 Ps[4][16 * 64];

  const int fr = l & 15;
  const int fg = (l >> 4) << 3;
  const int fswz = (fr & 7) << 3;

  const int qrow = q0 + w * 16 + fr;
  const size_t qbase = (size_t)(b * 1024 + qrow) * 2048 + h * 64 + fg;
  const s16x8 aq0 = *(const s16x8*)(qk + qbase);
  const s16x8 aq1 = *(const s16x8*)(qk + qbase + 32);

  f32x4 acc_o[4];
#pragma unroll
  for (int i = 0; i < 4; ++i)
#pragma unroll
    for (int e = 0; e < 4; ++e) acc_o[i][e] = 0.f;
  float m_i[4] = {-INFINITY, -INFINITY, -INFINITY, -INFINITY};
  float l_i[4] = {0.f, 0.f, 0.f, 0.f};

  const int sr = (w << 3) + (l >> 3);
  const int scs = (((l & 7) ^ ((l >> 3) & 7)) << 3);
  const u16* ksrc = qk + (size_t)(b * 1024 + sr) * 2048 + 1024 + h * 64 + scs;
  const u16* vsrc = Vt + ((size_t)((b * 16 + h) * 64 + sr)) * 1024 + scs;
  const int ldst = (w << 9);

#define ASTAGE(buf, kb_)                                                     \
  do {                                                                       \
    gload_lds16(ksrc + (size_t)(kb_) * 2048, &Ks[buf][ldst]);                \
    gload_lds16(ksrc + (size_t)((kb_) + 32) * 2048, &Ks[buf][2048 + ldst]);  \
    gload_lds16(vsrc + (kb_), &Vs[buf][ldst]);                               \
    gload_lds16(vsrc + (kb_) + 32 * 1024, &Vs[buf][2048 + ldst]);            \
  } while (0)

  const int qrow_c = q0 + w * 16 + ((l >> 4) << 2);
  u16* Psw = &Ps[w][0];
  const int nkt = qt + 1;

  ASTAGE(0, 0);
  int cur = 0;
  for (int kt = 0; kt < nkt; ++kt) {
    const int kb = kt << 6;
    if (kt + 1 < nkt) {
      ASTAGE(cur ^ 1, (kt + 1) << 6);
      asm volatile("s_waitcnt vmcnt(4)" ::: "memory");
    } else {
      asm volatile("s_waitcnt vmcnt(0)" ::: "memory");
    }
    __builtin_amdgcn_s_barrier();
    __builtin_amdgcn_sched_barrier(0);

    f32x4 s[4];
#pragma unroll
    for (int n = 0; n < 4; ++n) {
#pragma unroll
      for (int e = 0; e < 4; ++e) s[n][e] = 0.f;
      s16x8 bk0 = *(const s16x8*)(&Ks[cur][(n * 16 + fr) * 64 + (fg ^ fswz)]);
      s16x8 bk1 = *(const s16x8*)(&Ks[cur][(n * 16 + fr) * 64 + ((32 + fg) ^ fswz)]);
      s[n] = __builtin_amdgcn_mfma_f32_16x16x32_bf16(aq0, bk0, s[n], 0, 0, 0);
      s[n] = __builtin_amdgcn_mfma_f32_16x16x32_bf16(aq1, bk1, s[n], 0, 0, 0);
    }
#pragma unroll
    for (int n = 0; n < 4; ++n)
#pragma unroll
      for (int e = 0; e < 4; ++e) s[n][e] *= 0.125f;
    if (kt == nkt - 1 && kb == q0) {
#pragma unroll
      for (int n = 0; n < 4; ++n) {
        int kc = kb + n * 16 + fr;
#pragma unroll
        for (int r = 0; r < 4; ++r)
          if (kc > qrow_c + r) s[n][r] = -INFINITY;
      }
    }

    float rm[4], fac[4];
#pragma unroll
    for (int r = 0; r < 4; ++r)
      rm[r] = fmaxf(fmaxf(s[0][r], s[1][r]), fmaxf(s[2][r], s[3][r]));
#pragma unroll
    for (int off = 1; off < 16; off <<= 1)
#pragma unroll
      for (int r = 0; r < 4; ++r) rm[r] = fmaxf(rm[r], __shfl_xor(rm[r], off));
#pragma unroll
    for (int r = 0; r < 4; ++r) {
      float mn = fmaxf(m_i[r], rm[r]);
      fac[r] = __expf(m_i[r] - mn);
      m_i[r] = mn;
    }
    float rs[4] = {0.f, 0.f, 0.f, 0.f};
    float pb[4][4];
#pragma unroll
    for (int n = 0; n < 4; ++n)
#pragma unroll
      for (int r = 0; r < 4; ++r) {
        float pv = __expf(s[n][r] - m_i[r]);
        pb[n][r] = pv;
        rs[r] += pv;
      }
#pragma unroll
    for (int off = 1; off < 16; off <<= 1)
#pragma unroll
      for (int r = 0; r < 4; ++r) rs[r] += __shfl_xor(rs[r], off);
#pragma unroll
    for (int r = 0; r < 4; ++r) l_i[r] = l_i[r] * fac[r] + rs[r];
#pragma unroll
    for (int dt = 0; dt < 4; ++dt)
#pragma unroll
      for (int r = 0; r < 4; ++r) acc_o[dt][r] *= fac[r];

#pragma unroll
    for (int n = 0; n < 4; ++n)
#pragma unroll
      for (int r = 0; r < 4; ++r) {
        int prow = ((l >> 4) << 2) + r;
        Psw[prow * 64 + ((n * 16 + fr) ^ ((prow & 7) << 3))] = f2bf(pb[n][r]);
      }
    asm volatile("s_waitcnt lgkmcnt(0)" ::: "memory");
    __builtin_amdgcn_sched_barrier(0);

    s16x8 pa0 = *(const s16x8*)(Psw + fr * 64 + (fg ^ fswz));
    s16x8 pa1 = *(const s16x8*)(Psw + fr * 64 + ((32 + fg) ^ fswz));
#pragma unroll
    for (int dt = 0; dt < 4; ++dt) {
      s16x8 bv0 = *(const s16x8*)(&Vs[cur][(dt * 16 + fr) * 64 + (fg ^ fswz)]);
      s16x8 bv1 = *(const s16x8*)(&Vs[cur][(dt * 16 + fr) * 64 + ((32 + fg) ^ fswz)]);
      acc_o[dt] = __builtin_amdgcn_mfma_f32_16x16x32_bf16(pa0, bv0, acc_o[dt], 0, 0, 0);
      acc_o[dt] = __builtin_amdgcn_mfma_f32_16x16x32_bf16(pa1, bv1, acc_o[dt], 0, 0, 0);
    }
    asm volatile("s_waitcnt lgkmcnt(0)" ::: "memory");
    __builtin_amdgcn_sched_barrier(0);
    __builtin_amdgcn_s_barrier();
    cur ^= 1;
  }
#undef ASTAGE

  float invl[4];
#pragma unroll
  for (int r = 0; r < 4; ++r) invl[r] = 1.f / l_i[r];
#pragma unroll
  for (int dt = 0; dt < 4; ++dt)
#pragma unroll
    for (int r = 0; r < 4; ++r) {
      size_t idx = (size_t)(b * 1024 + qrow_c + r) * 1024 + h * 64 + dt * 16 + fr;
      out[idx] = f2bf(acc_o[dt][r] * invl[r]);
    }
}

// ---------------- final depth-2 ----------------
template<int NPART>
__global__ __launch_bounds__(256) void depth2_kernel(
    const u16* __restrict__ parts, const u16* __restrict__ mixrest,
    const float* __restrict__ beta, float* __restrict__ Hout)
{
  const size_t MN = (size_t)4096 * 1024;
  const size_t stride = (size_t)gridDim.x * 256;
  const size_t n8 = (size_t)BB * LL * RR * DD / 8;
  for (size_t i = (size_t)blockIdx.x * 256 + threadIdx.x; i < n8; i += stride) {
    size_t e = i * 8;
    int d = (int)(e & 1023);
    int n = (int)((e >> 10) & 3);
    size_t bl = e >> 12;
    float be = beta[bl * 4 + n];
    float f[8];
#pragma unroll
    for (int j = 0; j < 8; ++j) f[j] = 0.f;
#pragma unroll
    for (int p = 0; p < NPART; ++p) {
      s16x8 v = *(const s16x8*)&parts[p * MN + bl * 1024 + d];
#pragma unroll
      for (int j = 0; j < 8; ++j) f[j] += bf2f((u16)v[j]);
    }
    s16x8 m = *(const s16x8*)&mixrest[e];
    float4 o0, o1;
    o0.x = be * f[0] + bf2f((u16)m[0]); o0.y = be * f[1] + bf2f((u16)m[1]);
    o0.z = be * f[2] + bf2f((u16)m[2]); o0.w = be * f[3] + bf2f((u16)m[3]);
    o1.x = be * f[4] + bf2f((u16)m[4]); o1.y = be * f[5] + bf2f((u16)m[5]);
    o1.z = be * f[6] + bf2f((u16)m[6]); o1.w = be * f[7] + bf2f((u16)m[7]);
    *(float4*)&Hout[e] = o0;
    *(float4*)&Hout[e + 4] = o1;
  }
}

extern "C" void kernel_launch(void* const* d_in, const int* in_sizes, int n_in,
                              void* d_out, int out_size, void* d_ws, size_t ws_size,
                              hipStream_t stream) {
  const float* H       = (const float*)d_in[0];
  const float* hc1_nw  = (const float*)d_in[1];
  const float* hc1_afn = (const float*)d_in[2];
  const float* hc1_bfn = (const float*)d_in[3];
  const float* hc1_as  = (const float*)d_in[4];
  const float* hc1_bs  = (const float*)d_in[5];
  const float* hc1_sa  = (const float*)d_in[6];
  const float* hc1_sb  = (const float*)d_in[7];
  const float* attn_nw = (const float*)d_in[8];
  const float* qkv_w   = (const float*)d_in[9];
  const float* out_w   = (const float*)d_in[10];
  const float* hc2_nw  = (const float*)d_in[11];
  const float* hc2_afn = (const float*)d_in[12];
  const float* hc2_bfn = (const float*)d_in[13];
  const float* hc2_as  = (const float*)d_in[14];
  const float* hc2_bs  = (const float*)d_in[15];
  const float* hc2_sa  = (const float*)d_in[16];
  const float* hc2_sb  = (const float*)d_in[17];
  const float* ffn_nw  = (const float*)d_in[18];
  const float* fc1_w   = (const float*)d_in[19];
  const float* fc2_w   = (const float*)d_in[20];
  float* Hout = (float*)d_out;

  char* wsp = (char*)d_ws;
  size_t off = 0;
  auto carve = [&](size_t bytes) {
    void* p = wsp + off;
    off = (off + bytes + 255) & ~(size_t)255;
    return p;
  };
  const size_t MN = (size_t)4096 * 1024;
  u16* wq_bf   = (u16*)carve((size_t)3072 * 1024 * 2);
  u16* wo_bf   = (u16*)carve((size_t)1024 * 1024 * 2);
  u16* w1_bf   = (u16*)carve((size_t)4096 * 1024 * 2);
  u16* w2_bf   = (u16*)carve((size_t)4096 * 1024 * 2);
  u16* xbf     = (u16*)carve((size_t)4096 * 1024 * 2);
  u16* mixrest = (u16*)carve((size_t)4096 * 4096 * 2);
  float* beta1 = (float*)carve((size_t)16384 * 4);
  float* beta2 = (float*)carve((size_t)16384 * 4);
  char* uregion = (char*)carve((size_t)32 * 1024 * 1024);
  u16* qk_bf   = (u16*)uregion;
  u16* Vt      = (u16*)(uregion + (size_t)16 * 1024 * 1024);
  u16* g1_bf   = (u16*)uregion;
  u16* attn_bf = (u16*)carve((size_t)4096 * 1024 * 2);
  u16* pp      = (u16*)carve((size_t)4 * MN * 2);

  // 1. width1 (+ pre-attn RMS) with parity-interleaved weight-cvt
  width_kernel<0, true><<<2048, 256, 0, stream>>>(H, nullptr, nullptr, nullptr,
      hc1_nw, hc1_afn, hc1_bfn, hc1_as, hc1_bs, hc1_sa, hc1_sb, attn_nw,
      mixrest, beta1, xbf,
      qkv_w, out_w, fc1_w, fc2_w, wq_bf, wo_bf, w1_bf, w2_bf);
  // 2. qkv -> bf16 Q,K + transposed V (128^2)
  gemm_bt_kernel<2, 1><<<768, 256, 0, stream>>>(xbf, wq_bf, qk_bf, Vt, 4096, 3072, 1024);
  // 3. attention (MFMA flash, XCD-local)
  attn_mfma_kernel<<<1024, 256, 0, stream>>>(qk_bf, Vt, attn_bf);
  // 4. out projection, split-K=2 -> bf16 partials (128^2, 512 blocks)
  gemm_bt_kernel<0, 2><<<512, 256, 0, stream>>>(attn_bf, wo_bf, pp, nullptr, 4096, 1024, 1024);
  // 5. depth1 + width2 (+ pre-ffn RMS); mixrest in-place
  width_kernel<2, false><<<1024, 256, 0, stream>>>(nullptr, mixrest, beta1, pp,
      hc2_nw, hc2_afn, hc2_bfn, hc2_as, hc2_bs, hc2_sa, hc2_sb, ffn_nw,
      mixrest, beta2, xbf,
      nullptr, nullptr, nullptr, nullptr, nullptr, nullptr, nullptr, nullptr);
  // 6. fc1 + gelu -> bf16 (128^2, 1024 blocks, 4/CU)
  gemm_bt_kernel<1, 1><<<1024, 256, 0, stream>>>(xbf, w1_bf, g1_bf, nullptr, 4096, 4096, 1024);
  // 7. fc2, split-K=4 -> bf16 partials (128^2)
  gemm_bt_kernel<0, 4><<<1024, 256, 0, stream>>>(g1_bf, w2_bf, pp, nullptr, 4096, 1024, 4096);
  // 8. depth2 -> output
  depth2_kernel<4><<<4096, 256, 0, stream>>>(pp, mixrest, beta2, Hout);
}

// Round 18
// 283.043 us; speedup vs baseline: 1.0156x; 1.0156x over previous
//
#include <hip/hip_runtime.h>
#include <math.h>

#define BB 4
#define LL 1024
#define RR 4
#define DD 1024
#define EPSV 1e-6f

typedef short s16x8 __attribute__((ext_vector_type(8)));
typedef float f32x4 __attribute__((ext_vector_type(4)));
typedef unsigned short u16;

__device__ inline unsigned short f2bf(float x) {
  unsigned u = __builtin_bit_cast(unsigned, x);
  unsigned r = (u + 0x7fffu + ((u >> 16) & 1u)) >> 16;
  return (unsigned short)r;
}
__device__ inline float bf2f(u16 x) {
  return __builtin_bit_cast(float, (unsigned)x << 16);
}
__device__ inline float fast_tanh(float x) {
  float e = __expf(2.f * x);
  return 1.f - 2.f / (e + 1.f);
}

__device__ inline float wred_xor(float v) {
#pragma unroll
  for (int off = 1; off < 64; off <<= 1) v += __shfl_xor(v, off);
  return v;
}

__device__ inline void gload_lds16(const u16* g, u16* l) {
  __builtin_amdgcn_global_load_lds(
      (const __attribute__((address_space(1))) unsigned int*)g,
      (__attribute__((address_space(3))) unsigned int*)l, 16, 0, 0);
}

// ---------------- width (hyper-connection), wave-per-row (R14/R16 proven), interleaved cvt ------
template<int NP, bool CVT>
__global__ __launch_bounds__(256) void width_kernel(
    const float* __restrict__ Hin,
    const u16* __restrict__ mixrest_in,
    const float* __restrict__ beta_in,
    const u16* __restrict__ pp,
    const float* __restrict__ hc_norm_w,
    const float* __restrict__ alpha_fn,
    const float* __restrict__ beta_fn,
    const float* __restrict__ a_scale,
    const float* __restrict__ b_scale,
    const float* __restrict__ s_alpha,
    const float* __restrict__ s_beta,
    const float* __restrict__ post_norm_w,
    u16* __restrict__ mixrest_out,
    float* __restrict__ beta_out,
    u16* __restrict__ x_out,
    const float* __restrict__ cvt_s0, const float* __restrict__ cvt_s1,
    const float* __restrict__ cvt_s2, const float* __restrict__ cvt_s3,
    u16* __restrict__ cvt_d0, u16* __restrict__ cvt_d1,
    u16* __restrict__ cvt_d2, u16* __restrict__ cvt_d3)
{
  if (CVT && (blockIdx.x & 1)) {
    const int n0 = 786432, n1 = 262144, n2 = 1048576, n3 = 1048576;
    const int total = n0 + n1 + n2 + n3;
    for (int i = (blockIdx.x >> 1) * 256 + threadIdx.x; i < total; i += 1024 * 256) {
      const float4* src; ushort4* dst; int j;
      if (i < n0)                { src = (const float4*)cvt_s0; dst = (ushort4*)cvt_d0; j = i; }
      else if (i < n0 + n1)      { src = (const float4*)cvt_s1; dst = (ushort4*)cvt_d1; j = i - n0; }
      else if (i < n0 + n1 + n2) { src = (const float4*)cvt_s2; dst = (ushort4*)cvt_d2; j = i - n0 - n1; }
      else                       { src = (const float4*)cvt_s3; dst = (ushort4*)cvt_d3; j = i - n0 - n1 - n2; }
      float4 v = src[j];
      ushort4 o;
      o.x = f2bf(v.x); o.y = f2bf(v.y); o.z = f2bf(v.z); o.w = f2bf(v.w);
      dst[j] = o;
    }
    return;
  }
  const int blw = CVT ? (blockIdx.x >> 1) : blockIdx.x;

  const size_t MN = (size_t)4096 * 1024;
  const int l = threadIdx.x & 63, w = threadIdx.x >> 6;
  const int bl = blw * 4 + w;
  const int d0 = l << 2;

  float4 h[4][4];
  if (NP > 0) {
    float be[4];
#pragma unroll
    for (int n = 0; n < 4; ++n) be[n] = beta_in[bl * 4 + n];
#pragma unroll
    for (int i = 0; i < 4; ++i) {
      const int d = i * 256 + d0;
      float4 s; s.x = 0.f; s.y = 0.f; s.z = 0.f; s.w = 0.f;
#pragma unroll
      for (int p = 0; p < (NP > 0 ? NP : 1); ++p) {
        ushort4 v = *(const ushort4*)&pp[p * MN + (size_t)bl * 1024 + d];
        s.x += bf2f(v.x); s.y += bf2f(v.y); s.z += bf2f(v.z); s.w += bf2f(v.w);
      }
#pragma unroll
      for (int n = 0; n < 4; ++n) {
        ushort4 mr = *(const ushort4*)&mixrest_in[(size_t)bl * 4096 + n * 1024 + d];
        h[n][i].x = be[n] * s.x + bf2f(mr.x);
        h[n][i].y = be[n] * s.y + bf2f(mr.y);
        h[n][i].z = be[n] * s.z + bf2f(mr.z);
        h[n][i].w = be[n] * s.w + bf2f(mr.w);
      }
    }
  } else {
#pragma unroll
    for (int i = 0; i < 4; ++i) {
      const int d = i * 256 + d0;
#pragma unroll
      for (int n = 0; n < 4; ++n)
        h[n][i] = *(const float4*)&Hin[(size_t)bl * 4096 + n * 1024 + d];
    }
  }

  float inv[4];
#pragma unroll
  for (int n = 0; n < 4; ++n) {
    float a = 0.f;
#pragma unroll
    for (int i = 0; i < 4; ++i)
      a += h[n][i].x * h[n][i].x + h[n][i].y * h[n][i].y +
           h[n][i].z * h[n][i].z + h[n][i].w * h[n][i].w;
    a = wred_xor(a);
    inv[n] = 1.f / (sqrtf(a * (1.f / 1024.f)) + EPSV);
  }

  float dots[4][6];
#pragma unroll
  for (int n = 0; n < 4; ++n)
#pragma unroll
    for (int k = 0; k < 6; ++k) dots[n][k] = 0.f;
#pragma unroll
  for (int i = 0; i < 4; ++i) {
    const int d = i * 256 + d0;
    float4 nw = *(const float4*)&hc_norm_w[d];
    float4 bfv4 = *(const float4*)&beta_fn[d];
    float4 A0 = *(const float4*)&alpha_fn[d * 5];
    float4 A1 = *(const float4*)&alpha_fn[d * 5 + 4];
    float4 A2 = *(const float4*)&alpha_fn[d * 5 + 8];
    float4 A3 = *(const float4*)&alpha_fn[d * 5 + 12];
    float4 A4 = *(const float4*)&alpha_fn[d * 5 + 16];
    const float af[4][5] = {
        {A0.x, A0.y, A0.z, A0.w, A1.x},
        {A1.y, A1.z, A1.w, A2.x, A2.y},
        {A2.z, A2.w, A3.x, A3.y, A3.z},
        {A3.w, A4.x, A4.y, A4.z, A4.w}};
    const float nwv[4] = {nw.x, nw.y, nw.z, nw.w};
    const float bfl[4] = {bfv4.x, bfv4.y, bfv4.z, bfv4.w};
#pragma unroll
    for (int j = 0; j < 4; ++j) {
      const float wj = nwv[j];
#pragma unroll
      for (int n = 0; n < 4; ++n) {
        const float hw = (j == 0 ? h[n][i].x : j == 1 ? h[n][i].y : j == 2 ? h[n][i].z : h[n][i].w) * wj;
        dots[n][0] += hw * af[j][0];
        dots[n][1] += hw * af[j][1];
        dots[n][2] += hw * af[j][2];
        dots[n][3] += hw * af[j][3];
        dots[n][4] += hw * af[j][4];
        dots[n][5] += hw * bfl[j];
      }
    }
  }
  const float as = a_scale[0], bs = b_scale[0];
  float alpha[4][5], betav[4];
#pragma unroll
  for (int n = 0; n < 4; ++n) {
#pragma unroll
    for (int k = 0; k < 5; ++k) {
      float r = wred_xor(dots[n][k]);
      alpha[n][k] = fast_tanh(r * inv[n]) * as + s_alpha[n * 5 + k];
    }
    float rb = wred_xor(dots[n][5]);
    betav[n] = fast_tanh(rb * inv[n]) * bs + s_beta[n];
  }
  if (l == 0) {
#pragma unroll
    for (int n = 0; n < 4; ++n) beta_out[bl * 4 + n] = betav[n];
  }

  float4 mix0[4];
#pragma unroll
  for (int i = 0; i < 4; ++i) {
    const int d = i * 256 + d0;
#pragma unroll
    for (int k = 0; k < 5; ++k) {
      const float c0 = alpha[0][k], c1 = alpha[1][k], c2 = alpha[2][k], c3 = alpha[3][k];
      float4 mv;
      mv.x = c0 * h[0][i].x + c1 * h[1][i].x + c2 * h[2][i].x + c3 * h[3][i].x;
      mv.y = c0 * h[0][i].y + c1 * h[1][i].y + c2 * h[2][i].y + c3 * h[3][i].y;
      mv.z = c0 * h[0][i].z + c1 * h[1][i].z + c2 * h[2][i].z + c3 * h[3][i].z;
      mv.w = c0 * h[0][i].w + c1 * h[1][i].w + c2 * h[2][i].w + c3 * h[3][i].w;
      if (k == 0) {
        mix0[i] = mv;
      } else {
        ushort4 ov;
        ov.x = f2bf(mv.x); ov.y = f2bf(mv.y); ov.z = f2bf(mv.z); ov.w = f2bf(mv.w);
        *(ushort4*)&mixrest_out[(size_t)bl * 4096 + (size_t)(k - 1) * 1024 + d] = ov;
      }
    }
  }

  float a0s = 0.f;
#pragma unroll
  for (int i = 0; i < 4; ++i)
    a0s += mix0[i].x * mix0[i].x + mix0[i].y * mix0[i].y +
           mix0[i].z * mix0[i].z + mix0[i].w * mix0[i].w;
  a0s = wred_xor(a0s);
  const float iv0 = 1.f / (sqrtf(a0s * (1.f / 1024.f)) + EPSV);
#pragma unroll
  for (int i = 0; i < 4; ++i) {
    const int d = i * 256 + d0;
    float4 pw = *(const float4*)&post_norm_w[d];
    ushort4 ov;
    ov.x = f2bf(pw.x * mix0[i].x * iv0);
    ov.y = f2bf(pw.y * mix0[i].y * iv0);
    ov.z = f2bf(pw.z * mix0[i].z * iv0);
    ov.w = f2bf(pw.w * mix0[i].w * iv0);
    *(ushort4*)&x_out[(size_t)bl * 1024 + d] = ov;
  }
}

// ---------------- bf16 GEMM 128x128 (R7 proven) — all four GEMMs ----------------
template<int EPI, int SPLIT>
__global__ __launch_bounds__(256, 4) void gemm_bt_kernel(
    const u16* __restrict__ A, const u16* __restrict__ W,
    u16* __restrict__ Cb, u16* __restrict__ Vt,
    int M, int N, int K)
{
  __shared__ __align__(16) u16 LDSb[2][2][128 * 32];
  const int tn = N >> 7, tm = M >> 7;
  int bid = blockIdx.x;
  const int nwg = gridDim.x;
  if ((nwg & 7) == 0) bid = (bid & 7) * (nwg >> 3) + (bid >> 3);
  const int ts = tm * tn;
  const int sK = bid / ts;
  const int tb = bid - sK * ts;
  const int bm = tb / tn, bn = tb % tn;
  const int Kc = K / SPLIT;
  const int kbeg = sK * Kc;

  const int t = threadIdx.x, l = t & 63, w = t >> 6;
  const int wr = w >> 1, wc = w & 1;
  const int m0 = bm << 7, n0 = bn << 7;
  const int ssc = (((l & 3) ^ ((l >> 3) & 3)) << 3);
  const int srA = m0 + (w << 5) + (l >> 2);
  const int srB = n0 + (w << 5) + (l >> 2);
  const int ldso = (w << 10);
  const int fr = l & 15, g4 = l >> 4;
  const int fc8 = ((g4 ^ ((l >> 1) & 3)) << 3);

  f32x4 acc[4][4];
#pragma unroll
  for (int i = 0; i < 4; ++i)
#pragma unroll
    for (int j = 0; j < 4; ++j)
#pragma unroll
      for (int e = 0; e < 4; ++e) acc[i][j][e] = 0.f;

  const u16* pa0 = A + (size_t)srA * K + kbeg + ssc;
  const u16* pa1 = A + (size_t)(srA + 16) * K + kbeg + ssc;
  const u16* pb0 = W + (size_t)srB * K + kbeg + ssc;
  const u16* pb1 = W + (size_t)(srB + 16) * K + kbeg + ssc;

#define STAGE(buf, koff)                                   \
  do {                                                     \
    gload_lds16(pa0 + (koff), &LDSb[buf][0][ldso]);        \
    gload_lds16(pa1 + (koff), &LDSb[buf][0][ldso + 512]);  \
    gload_lds16(pb0 + (koff), &LDSb[buf][1][ldso]);        \
    gload_lds16(pb1 + (koff), &LDSb[buf][1][ldso + 512]);  \
  } while (0)

  const int nt = Kc >> 5;
  STAGE(0, 0);
  int cur = 0;
  for (int kt = 0; kt < nt; ++kt) {
    if (kt + 1 < nt) {
      STAGE(cur ^ 1, (kt + 1) << 5);
      asm volatile("s_waitcnt vmcnt(4)" ::: "memory");
    } else {
      asm volatile("s_waitcnt vmcnt(0)" ::: "memory");
    }
    __builtin_amdgcn_s_barrier();
    __builtin_amdgcn_sched_barrier(0);
    s16x8 af[4], bfr[4];
#pragma unroll
    for (int m = 0; m < 4; ++m)
      af[m] = *(const s16x8*)(&LDSb[cur][0][(wr * 64 + m * 16 + fr) * 32 + fc8]);
#pragma unroll
    for (int n = 0; n < 4; ++n)
      bfr[n] = *(const s16x8*)(&LDSb[cur][1][(wc * 64 + n * 16 + fr) * 32 + fc8]);
#pragma unroll
    for (int m = 0; m < 4; ++m)
#pragma unroll
      for (int n = 0; n < 4; ++n)
        acc[m][n] = __builtin_amdgcn_mfma_f32_16x16x32_bf16(af[m], bfr[n], acc[m][n], 0, 0, 0);
    asm volatile("s_waitcnt lgkmcnt(0)" ::: "memory");
    __builtin_amdgcn_sched_barrier(0);
    __builtin_amdgcn_s_barrier();
    cur ^= 1;
  }
#undef STAGE

  if (EPI == 2 && n0 >= 2048) {
    const int rbv = m0 + wr * 64 + (g4 << 2);
    const int cbv = n0 + wc * 64 + fr;
#pragma unroll
    for (int m = 0; m < 4; ++m)
#pragma unroll
      for (int n = 0; n < 4; ++n) {
        int cc = cbv + n * 16 - 2048;
        int hh = cc >> 6, dd = cc & 63;
        int r0 = rbv + m * 16;
        ushort4 ov;
        ov.x = f2bf(acc[m][n][0]); ov.y = f2bf(acc[m][n][1]);
        ov.z = f2bf(acc[m][n][2]); ov.w = f2bf(acc[m][n][3]);
        *(ushort4*)&Vt[((size_t)((r0 >> 10) * 16 + hh) * 64 + dd) * 1024 + (r0 & 1023)] = ov;
      }
    return;
  }

  float* scr = (float*)LDSb;
  const int strideN = (EPI == 2) ? 2048 : N;
  u16* Cout = (SPLIT > 1) ? (Cb + (size_t)sK * M * N) : Cb;
#pragma unroll
  for (int r = 0; r < 2; ++r) {
    __syncthreads();
    if (wr == r) {
#pragma unroll
      for (int m = 0; m < 4; ++m)
#pragma unroll
        for (int n = 0; n < 4; ++n)
#pragma unroll
          for (int j = 0; j < 4; ++j) {
            int lr = m * 16 + (g4 << 2) + j;
            int col = wc * 64 + n * 16 + fr;
            scr[lr * 128 + (col ^ ((((lr >> 2) & 7)) << 3))] = acc[m][n][j];
          }
    }
    __syncthreads();
#pragma unroll
    for (int it = 0; it < 4; ++it) {
      int lr = it * 16 + (t >> 4);
      int key8 = ((lr >> 2) & 7) << 3;
      int lc = (t & 15) << 3;
      int cb0 = (lc ^ key8);
      f32x4 v0 = *(const f32x4*)&scr[lr * 128 + cb0];
      f32x4 v1 = *(const f32x4*)&scr[lr * 128 + cb0 + 4];
      float vv[8] = {v0[0], v0[1], v0[2], v0[3], v1[0], v1[1], v1[2], v1[3]};
      s16x8 ov;
#pragma unroll
      for (int c = 0; c < 8; ++c) {
        float v = vv[c];
        if (EPI == 1) v = 0.5f * v * (1.f + erff(v * 0.70710678118f));
        ov[c] = (short)f2bf(v);
      }
      size_t gr = (size_t)(m0 + r * 64 + lr);
      *(s16x8*)&Cout[gr * strideN + n0 + lc] = ov;
    }
  }
}

// ---------------- MFMA flash attention, causal (R9 proven) ----------------
__global__ __launch_bounds__(256) void attn_mfma_kernel(
    const u16* __restrict__ qk, const u16* __restrict__ Vt, u16* __restrict__ out)
{
  const int id = blockIdx.x;
  const int hb = id & 63, qt0 = id >> 6;
  const int b = hb >> 4, h = hb & 15;
  const int qt = (h & 1) ? (15 - qt0) : qt0;
  const int t = threadIdx.x, l = t & 63, w = t >> 6;
  const int q0 = qt << 6;
  __shared__ __align__(16) u16 Ks[2][64 * 64];
  __shared__ __align__(16) u16 Vs[2][64 * 64];
  __shared__ __align__(16) u16 Ps[4][16 * 64];

  const int fr = l & 15;
  const int fg = (l >> 4) << 3;
  const int fswz = (fr & 7) << 3;

  const int qrow = q0 + w * 16 + fr;
  const size_t qbase = (size_t)(b * 1024 + qrow) * 2048 + h * 64 + fg;
  const s16x8 aq0 = *(const s16x8*)(qk + qbase);
  const s16x8 aq1 = *(const s16x8*)(qk + qbase + 32);

  f32x4 acc_o[4];
#pragma unroll
  for (int i = 0; i < 4; ++i)
#pragma unroll
    for (int e = 0; e < 4; ++e) acc_o[i][e] = 0.f;
  float m_i[4] = {-INFINITY, -INFINITY, -INFINITY, -INFINITY};
  float l_i[4] = {0.f, 0.f, 0.f, 0.f};

  const int sr = (w << 3) + (l >> 3);
  const int scs = (((l & 7) ^ ((l >> 3) & 7)) << 3);
  const u16* ksrc = qk + (size_t)(b * 1024 + sr) * 2048 + 1024 + h * 64 + scs;
  const u16* vsrc = Vt + ((size_t)((b * 16 + h) * 64 + sr)) * 1024 + scs;
  const int ldst = (w << 9);

#define ASTAGE(buf, kb_)                                                     \
  do {                                                                       \
    gload_lds16(ksrc + (size_t)(kb_) * 2048, &Ks[buf][ldst]);                \
    gload_lds16(ksrc + (size_t)((kb_) + 32) * 2048, &Ks[buf][2048 + ldst]);  \
    gload_lds16(vsrc + (kb_), &Vs[buf][ldst]);                               \
    gload_lds16(vsrc + (kb_) + 32 * 1024, &Vs[buf][2048 + ldst]);            \
  } while (0)

  const int qrow_c = q0 + w * 16 + ((l >> 4) << 2);
  u16* Psw = &Ps[w][0];
  const int nkt = qt + 1;

  ASTAGE(0, 0);
  int cur = 0;
  for (int kt = 0; kt < nkt; ++kt) {
    const int kb = kt << 6;
    if (kt + 1 < nkt) {
      ASTAGE(cur ^ 1, (kt + 1) << 6);
      asm volatile("s_waitcnt vmcnt(4)" ::: "memory");
    } else {
      asm volatile("s_waitcnt vmcnt(0)" ::: "memory");
    }
    __builtin_amdgcn_s_barrier();
    __builtin_amdgcn_sched_barrier(0);

    f32x4 s[4];
#pragma unroll
    for (int n = 0; n < 4; ++n) {
#pragma unroll
      for (int e = 0; e < 4; ++e) s[n][e] = 0.f;
      s16x8 bk0 = *(const s16x8*)(&Ks[cur][(n * 16 + fr) * 64 + (fg ^ fswz)]);
      s16x8 bk1 = *(const s16x8*)(&Ks[cur][(n * 16 + fr) * 64 + ((32 + fg) ^ fswz)]);
      s[n] = __builtin_amdgcn_mfma_f32_16x16x32_bf16(aq0, bk0, s[n], 0, 0, 0);
      s[n] = __builtin_amdgcn_mfma_f32_16x16x32_bf16(aq1, bk1, s[n], 0, 0, 0);
    }
#pragma unroll
    for (int n = 0; n < 4; ++n)
#pragma unroll
      for (int e = 0; e < 4; ++e) s[n][e] *= 0.125f;
    if (kt == nkt - 1 && kb == q0) {
#pragma unroll
      for (int n = 0; n < 4; ++n) {
        int kc = kb + n * 16 + fr;
#pragma unroll
        for (int r = 0; r < 4; ++r)
          if (kc > qrow_c + r) s[n][r] = -INFINITY;
      }
    }

    float rm[4], fac[4];
#pragma unroll
    for (int r = 0; r < 4; ++r)
      rm[r] = fmaxf(fmaxf(s[0][r], s[1][r]), fmaxf(s[2][r], s[3][r]));
#pragma unroll
    for (int off = 1; off < 16; off <<= 1)
#pragma unroll
      for (int r = 0; r < 4; ++r) rm[r] = fmaxf(rm[r], __shfl_xor(rm[r], off));
#pragma unroll
    for (int r = 0; r < 4; ++r) {
      float mn = fmaxf(m_i[r], rm[r]);
      fac[r] = __expf(m_i[r] - mn);
      m_i[r] = mn;
    }
    float rs[4] = {0.f, 0.f, 0.f, 0.f};
    float pb[4][4];
#pragma unroll
    for (int n = 0; n < 4; ++n)
#pragma unroll
      for (int r = 0; r < 4; ++r) {
        float pv = __expf(s[n][r] - m_i[r]);
        pb[n][r] = pv;
        rs[r] += pv;
      }
#pragma unroll
    for (int off = 1; off < 16; off <<= 1)
#pragma unroll
      for (int r = 0; r < 4; ++r) rs[r] += __shfl_xor(rs[r], off);
#pragma unroll
    for (int r = 0; r < 4; ++r) l_i[r] = l_i[r] * fac[r] + rs[r];
#pragma unroll
    for (int dt = 0; dt < 4; ++dt)
#pragma unroll
      for (int r = 0; r < 4; ++r) acc_o[dt][r] *= fac[r];

#pragma unroll
    for (int n = 0; n < 4; ++n)
#pragma unroll
      for (int r = 0; r < 4; ++r) {
        int prow = ((l >> 4) << 2) + r;
        Psw[prow * 64 + ((n * 16 + fr) ^ ((prow & 7) << 3))] = f2bf(pb[n][r]);
      }
    asm volatile("s_waitcnt lgkmcnt(0)" ::: "memory");
    __builtin_amdgcn_sched_barrier(0);

    s16x8 pa0 = *(const s16x8*)(Psw + fr * 64 + (fg ^ fswz));
    s16x8 pa1 = *(const s16x8*)(Psw + fr * 64 + ((32 + fg) ^ fswz));
#pragma unroll
    for (int dt = 0; dt < 4; ++dt) {
      s16x8 bv0 = *(const s16x8*)(&Vs[cur][(dt * 16 + fr) * 64 + (fg ^ fswz)]);
      s16x8 bv1 = *(const s16x8*)(&Vs[cur][(dt * 16 + fr) * 64 + ((32 + fg) ^ fswz)]);
      acc_o[dt] = __builtin_amdgcn_mfma_f32_16x16x32_bf16(pa0, bv0, acc_o[dt], 0, 0, 0);
      acc_o[dt] = __builtin_amdgcn_mfma_f32_16x16x32_bf16(pa1, bv1, acc_o[dt], 0, 0, 0);
    }
    asm volatile("s_waitcnt lgkmcnt(0)" ::: "memory");
    __builtin_amdgcn_sched_barrier(0);
    __builtin_amdgcn_s_barrier();
    cur ^= 1;
  }
#undef ASTAGE

  float invl[4];
#pragma unroll
  for (int r = 0; r < 4; ++r) invl[r] = 1.f / l_i[r];
#pragma unroll
  for (int dt = 0; dt < 4; ++dt)
#pragma unroll
    for (int r = 0; r < 4; ++r) {
      size_t idx = (size_t)(b * 1024 + qrow_c + r) * 1024 + h * 64 + dt * 16 + fr;
      out[idx] = f2bf(acc_o[dt][r] * invl[r]);
    }
}

// ---------------- final depth-2 ----------------
template<int NPART>
__global__ __launch_bounds__(256) void depth2_kernel(
    const u16* __restrict__ parts, const u16* __restrict__ mixrest,
    const float* __restrict__ beta, float* __restrict__ Hout)
{
  const size_t MN = (size_t)4096 * 1024;
  const size_t stride = (size_t)gridDim.x * 256;
  const size_t n8 = (size_t)BB * LL * RR * DD / 8;
  for (size_t i = (size_t)blockIdx.x * 256 + threadIdx.x; i < n8; i += stride) {
    size_t e = i * 8;
    int d = (int)(e & 1023);
    int n = (int)((e >> 10) & 3);
    size_t bl = e >> 12;
    float be = beta[bl * 4 + n];
    float f[8];
#pragma unroll
    for (int j = 0; j < 8; ++j) f[j] = 0.f;
#pragma unroll
    for (int p = 0; p < NPART; ++p) {
      s16x8 v = *(const s16x8*)&parts[p * MN + bl * 1024 + d];
#pragma unroll
      for (int j = 0; j < 8; ++j) f[j] += bf2f((u16)v[j]);
    }
    s16x8 m = *(const s16x8*)&mixrest[e];
    float4 o0, o1;
    o0.x = be * f[0] + bf2f((u16)m[0]); o0.y = be * f[1] + bf2f((u16)m[1]);
    o0.z = be * f[2] + bf2f((u16)m[2]); o0.w = be * f[3] + bf2f((u16)m[3]);
    o1.x = be * f[4] + bf2f((u16)m[4]); o1.y = be * f[5] + bf2f((u16)m[5]);
    o1.z = be * f[6] + bf2f((u16)m[6]); o1.w = be * f[7] + bf2f((u16)m[7]);
    *(float4*)&Hout[e] = o0;
    *(float4*)&Hout[e + 4] = o1;
  }
}

extern "C" void kernel_launch(void* const* d_in, const int* in_sizes, int n_in,
                              void* d_out, int out_size, void* d_ws, size_t ws_size,
                              hipStream_t stream) {
  const float* H       = (const float*)d_in[0];
  const float* hc1_nw  = (const float*)d_in[1];
  const float* hc1_afn = (const float*)d_in[2];
  const float* hc1_bfn = (const float*)d_in[3];
  const float* hc1_as  = (const float*)d_in[4];
  const float* hc1_bs  = (const float*)d_in[5];
  const float* hc1_sa  = (const float*)d_in[6];
  const float* hc1_sb  = (const float*)d_in[7];
  const float* attn_nw = (const float*)d_in[8];
  const float* qkv_w   = (const float*)d_in[9];
  const float* out_w   = (const float*)d_in[10];
  const float* hc2_nw  = (const float*)d_in[11];
  const float* hc2_afn = (const float*)d_in[12];
  const float* hc2_bfn = (const float*)d_in[13];
  const float* hc2_as  = (const float*)d_in[14];
  const float* hc2_bs  = (const float*)d_in[15];
  const float* hc2_sa  = (const float*)d_in[16];
  const float* hc2_sb  = (const float*)d_in[17];
  const float* ffn_nw  = (const float*)d_in[18];
  const float* fc1_w   = (const float*)d_in[19];
  const float* fc2_w   = (const float*)d_in[20];
  float* Hout = (float*)d_out;

  char* wsp = (char*)d_ws;
  size_t off = 0;
  auto carve = [&](size_t bytes) {
    void* p = wsp + off;
    off = (off + bytes + 255) & ~(size_t)255;
    return p;
  };
  const size_t MN = (size_t)4096 * 1024;
  u16* wq_bf   = (u16*)carve((size_t)3072 * 1024 * 2);
  u16* wo_bf   = (u16*)carve((size_t)1024 * 1024 * 2);
  u16* w1_bf   = (u16*)carve((size_t)4096 * 1024 * 2);
  u16* w2_bf   = (u16*)carve((size_t)4096 * 1024 * 2);
  u16* xbf     = (u16*)carve((size_t)4096 * 1024 * 2);
  u16* mixrest = (u16*)carve((size_t)4096 * 4096 * 2);
  float* beta1 = (float*)carve((size_t)16384 * 4);
  float* beta2 = (float*)carve((size_t)16384 * 4);
  char* uregion = (char*)carve((size_t)32 * 1024 * 1024);
  u16* qk_bf   = (u16*)uregion;
  u16* Vt      = (u16*)(uregion + (size_t)16 * 1024 * 1024);
  u16* g1_bf   = (u16*)uregion;
  u16* attn_bf = (u16*)carve((size_t)4096 * 1024 * 2);
  u16* pp      = (u16*)carve((size_t)4 * MN * 2);

  // 1. width1 (+ pre-attn RMS) with parity-interleaved weight-cvt
  width_kernel<0, true><<<2048, 256, 0, stream>>>(H, nullptr, nullptr, nullptr,
      hc1_nw, hc1_afn, hc1_bfn, hc1_as, hc1_bs, hc1_sa, hc1_sb, attn_nw,
      mixrest, beta1, xbf,
      qkv_w, out_w, fc1_w, fc2_w, wq_bf, wo_bf, w1_bf, w2_bf);
  // 2. qkv -> bf16 Q,K + transposed V (128^2)
  gemm_bt_kernel<2, 1><<<768, 256, 0, stream>>>(xbf, wq_bf, qk_bf, Vt, 4096, 3072, 1024);
  // 3. attention (MFMA flash, XCD-local)
  attn_mfma_kernel<<<1024, 256, 0, stream>>>(qk_bf, Vt, attn_bf);
  // 4. out projection, split-K=2 -> bf16 partials (128^2, 512 blocks)
  gemm_bt_kernel<0, 2><<<512, 256, 0, stream>>>(attn_bf, wo_bf, pp, nullptr, 4096, 1024, 1024);
  // 5. depth1 + width2 (+ pre-ffn RMS); mixrest in-place
  width_kernel<2, false><<<1024, 256, 0, stream>>>(nullptr, mixrest, beta1, pp,
      hc2_nw, hc2_afn, hc2_bfn, hc2_as, hc2_bs, hc2_sa, hc2_sb, ffn_nw,
      mixrest, beta2, xbf,
      nullptr, nullptr, nullptr, nullptr, nullptr, nullptr, nullptr, nullptr);
  // 6. fc1 + gelu -> bf16 (128^2, 1024 blocks, 4/CU)
  gemm_bt_kernel<1, 1><<<1024, 256, 0, stream>>>(xbf, w1_bf, g1_bf, nullptr, 4096, 4096, 1024);
  // 7. fc2, split-K=4 -> bf16 partials (128^2)
  gemm_bt_kernel<0, 4><<<1024, 256, 0, stream>>>(g1_bf, w2_bf, pp, nullptr, 4096, 1024, 4096);
  // 8. depth2 -> output
  depth2_kernel<4><<<4096, 256, 0, stream>>>(pp, mixrest, beta2, Hout);
}